// Round 2
// baseline (842.773 us; speedup 1.0000x reference)
//
#include <hip/hip_runtime.h>

typedef __attribute__((ext_vector_type(8))) short bf16x8;
typedef __attribute__((ext_vector_type(4))) float f32x4;
typedef unsigned short u16;

#define NTOK   49
#define SCALE  0.17677669529663687f
#define NEGBIG -30000.0f

// ---- LDS layout (bytes). All section offsets & row strides multiple of 16.
#define QK_STRIDE   520                         // bf16 elems/row: 512 + 8 pad
#define QK_OFF      0
#define QK_BYTES    (NTOK * QK_STRIDE * 2)      // 50960
#define VT_STRIDE   72                          // cols: 64 (49 tokens + zero pad) + 8 pad
#define VT_OFF      (QK_OFF + QK_BYTES)         // 50960
#define VT_BYTES    (256 * VT_STRIDE * 2)       // 36864
#define R2_OFF      (VT_OFF + VT_BYTES)         // 87824  (x-tile, later P buffers)
#define X_STRIDE    264                         // 256 + 8 pad
#define P_STRIDE    72
#define P_WAVE_B    (NTOK * P_STRIDE * 2)       // 7056
#define R2_BYTES    (4 * P_WAVE_B)              // 28224 >= 49*264*2=25872
#define BIAS_OFF    (R2_OFF + R2_BYTES)         // 116048
#define BIAS_BYTES  2720                        // 169*8*2=2704, padded
#define IM_OFF      (BIAS_OFF + BIAS_BYTES)     // 118768
#define IM_BYTES    4816                        // 49*49*2=4802; flag at +4808
#define FLAG_OFF    (IM_OFF + 4808)
#define SMEM_BYTES  (IM_OFF + IM_BYTES)         // 123584

static __device__ __forceinline__ float b2f(u16 u) {
    return __uint_as_float(((unsigned int)u) << 16);
}
static __device__ __forceinline__ u16 f2b(float f) {
    unsigned int x = __float_as_uint(f);
    x += 0x7fffu + ((x >> 16) & 1u);      // RNE
    return (u16)(x >> 16);
}
// load 8 consecutive elements starting at element index eidx, as bf16x8
static __device__ __forceinline__ bf16x8 load8(const void* base, int eidx, int isbf) {
    if (isbf) return *(const bf16x8*)((const u16*)base + eidx);
    const float* f = (const float*)base + eidx;
    float4 a = *(const float4*)f;
    float4 c = *(const float4*)(f + 4);
    bf16x8 r;
    r[0] = (short)f2b(a.x); r[1] = (short)f2b(a.y); r[2] = (short)f2b(a.z); r[3] = (short)f2b(a.w);
    r[4] = (short)f2b(c.x); r[5] = (short)f2b(c.y); r[6] = (short)f2b(c.z); r[7] = (short)f2b(c.w);
    return r;
}
static __device__ __forceinline__ float loadf(const void* base, int i, int isbf) {
    return isbf ? b2f(((const u16*)base)[i]) : ((const float*)base)[i];
}

__global__ void __launch_bounds__(256, 1)
swin_fused_kernel(const void* __restrict__ x, const void* __restrict__ qkv_w,
                  const void* __restrict__ qkv_b, const void* __restrict__ proj_w,
                  const void* __restrict__ proj_b, const void* __restrict__ bias_tbl,
                  void* __restrict__ out)
{
    extern __shared__ __align__(16) char smem[];
    const int tid    = threadIdx.x;
    const int wv     = tid >> 6;
    const int lane   = tid & 63;
    const int lane15 = lane & 15;
    const int quad   = lane >> 4;
    const int crow   = quad << 2;       // C-layout row base within 16-tile

    const int win  = blockIdx.x;
    const int b    = win >> 6;
    const int wrem = win & 63;
    const int whi  = wrem >> 3;
    const int wwi  = wrem & 7;

    // ---------------- dtype sniff (block-uniform) ----------------
    // bf16 N(0,0.02) data: u16 exponent field in ~[107,125]. f32 data read as
    // u16 at even indices = low mantissa halves -> exponent field uniform.
    int good = 0;
#pragma unroll
    for (int j = 0; j < 8; ++j) {
        u16 u = ((const u16*)qkv_w)[tid * 16 + j * 2];
        int e = (u >> 7) & 0xff;
        good += (e == 0 || (e >= 100 && e <= 140)) ? 1 : 0;
    }
#pragma unroll
    for (int d = 1; d < 64; d <<= 1) good += __shfl_xor(good, d, 64);
    if (tid == 0) *(int*)(smem + FLAG_OFF) = 0;
    __syncthreads();
    if (lane == 0) atomicAdd((int*)(smem + FLAG_OFF), good);
    __syncthreads();
    const int isbf = (*(int*)(smem + FLAG_OFF) > 1024) ? 1 : 0;

    // ---------------- stage 0: gather + tables + zero vt ----------------
    for (int i = tid; i < NTOK * 32; i += 256) {
        int tok = i >> 5, ch = i & 31;
        int rt = tok / 7, ct = tok - (tok / 7) * 7;
        int sh_ = (whi * 7 + rt + 3) % 56;
        int sw_ = (wwi * 7 + ct + 3) % 56;
        int idx = ((b * 56 + sh_) * 56 + sw_) * 256 + ch * 8;
        *(bf16x8*)(smem + R2_OFF + tok * (X_STRIDE * 2) + ch * 16) = load8(x, idx, isbf);
    }
    {
        bf16x8 z8 = {0, 0, 0, 0, 0, 0, 0, 0};
        for (int i = tid; i < 256 * VT_STRIDE / 8; i += 256)
            *(bf16x8*)(smem + VT_OFF + i * 16) = z8;
    }
    for (int i = tid; i < NTOK * NTOK; i += 256) {
        int m = i / 49, n = i - (i / 49) * 49;
        int rm = m / 7, cm = m - rm * 7;
        int rn = n / 7, cn = n - rn * 7;
        int idx = (rm - rn + 6) * 13 + (cm - cn + 6);            // 0..168
        int ghm = whi * 7 + rm, gwm = wwi * 7 + cm;
        int ghn = whi * 7 + rn, gwn = wwi * 7 + cn;
        int regm = (ghm < 49 ? 0 : (ghm < 53 ? 1 : 2)) * 3 + (gwm < 49 ? 0 : (gwm < 53 ? 1 : 2));
        int regn = (ghn < 49 ? 0 : (ghn < 53 ? 1 : 2)) * 3 + (gwn < 49 ? 0 : (gwn < 53 ? 1 : 2));
        u16 v = (u16)(idx | ((regm != regn) ? 0x8000u : 0u));
        *(u16*)(smem + IM_OFF + i * 2) = v;
    }
    for (int i = tid; i < 169 * 8; i += 256)
        *(u16*)(smem + BIAS_OFF + i * 2) = f2b(loadf(bias_tbl, i, isbf));

    __syncthreads();

    int mrowc[4];
#pragma unroll
    for (int t = 0; t < 4; ++t) {
        int m = t * 16 + lane15;
        mrowc[t] = m < 49 ? m : 48;
    }

    // ---------------- stage 1: QKV GEMM (M=64, N=768, K=256) ----------------
    for (int ci = 0; ci < 12; ++ci) {
        int c = wv + 4 * ci;
        int o = c * 16 + lane15;             // output channel 0..767
        f32x4 acc[4];
#pragma unroll
        for (int t = 0; t < 4; ++t) acc[t] = (f32x4){0.f, 0.f, 0.f, 0.f};
#pragma unroll
        for (int ks = 0; ks < 8; ++ks) {
            bf16x8 bfrag = load8(qkv_w, o * 256 + ks * 32 + quad * 8, isbf);
            int coffb = (ks * 32 + quad * 8) * 2;
#pragma unroll
            for (int tm = 0; tm < 4; ++tm) {
                bf16x8 afrag = *(const bf16x8*)(smem + R2_OFF + mrowc[tm] * (X_STRIDE * 2) + coffb);
                acc[tm] = __builtin_amdgcn_mfma_f32_16x16x32_bf16(afrag, bfrag, acc[tm], 0, 0, 0);
            }
        }
        float bias = loadf(qkv_b, o, isbf);
        int isv = (o >= 512);
#pragma unroll
        for (int tm = 0; tm < 4; ++tm) {
#pragma unroll
            for (int r = 0; r < 4; ++r) {
                int row = tm * 16 + crow + r;
                if (row < 49) {
                    u16 hv = f2b(acc[tm][r] + bias);
                    if (!isv) *(u16*)(smem + QK_OFF + (row * QK_STRIDE + o) * 2) = hv;
                    else      *(u16*)(smem + VT_OFF + ((o - 512) * VT_STRIDE + row) * 2) = hv;
                }
            }
        }
    }
    __syncthreads();

    // ---------------- stage 2: attention, 2 heads per wave ----------------
    char* pbase = smem + R2_OFF + wv * P_WAVE_B;
    for (int hi = 0; hi < 2; ++hi) {
        int h = wv * 2 + hi;
        int qoffb = (h * 32 + quad * 8) * 2;
        int koffb = (256 + h * 32 + quad * 8) * 2;
        bf16x8 aq[4], bk[4];
#pragma unroll
        for (int t = 0; t < 4; ++t) {
            aq[t] = *(const bf16x8*)(smem + QK_OFF + mrowc[t] * (QK_STRIDE * 2) + qoffb);
            bk[t] = *(const bf16x8*)(smem + QK_OFF + mrowc[t] * (QK_STRIDE * 2) + koffb);
        }
        f32x4 s[4][4];
#pragma unroll
        for (int tm = 0; tm < 4; ++tm)
#pragma unroll
            for (int tn = 0; tn < 4; ++tn) {
                f32x4 z = {0.f, 0.f, 0.f, 0.f};
                s[tm][tn] = __builtin_amdgcn_mfma_f32_16x16x32_bf16(aq[tm], bk[tn], z, 0, 0, 0);
            }
#pragma unroll
        for (int tm = 0; tm < 4; ++tm)
#pragma unroll
            for (int tn = 0; tn < 4; ++tn) {
                int n = tn * 16 + lane15;
#pragma unroll
                for (int r = 0; r < 4; ++r) {
                    float val;
                    if (n < 49) {
                        int m = tm * 16 + crow + r;
                        int mc = m < 49 ? m : 48;
                        u16 im = *(const u16*)(smem + IM_OFF + (mc * 49 + n) * 2);
                        float bv = b2f(*(const u16*)(smem + BIAS_OFF + (((int)(im & 0x7fffu)) * 8 + h) * 2));
                        val = s[tm][tn][r] * SCALE + bv + ((im & 0x8000u) ? -100.0f : 0.0f);
                    } else {
                        val = NEGBIG;
                    }
                    s[tm][tn][r] = val;
                }
            }
        float rmax[4][4], rinv[4][4];
#pragma unroll
        for (int tm = 0; tm < 4; ++tm)
#pragma unroll
            for (int r = 0; r < 4; ++r) {
                float mv = fmaxf(fmaxf(s[tm][0][r], s[tm][1][r]), fmaxf(s[tm][2][r], s[tm][3][r]));
#pragma unroll
                for (int d = 1; d < 16; d <<= 1) mv = fmaxf(mv, __shfl_xor(mv, d, 16));
                rmax[tm][r] = mv;
            }
#pragma unroll
        for (int tm = 0; tm < 4; ++tm)
#pragma unroll
            for (int r = 0; r < 4; ++r) {
                float ssum = 0.f;
#pragma unroll
                for (int tn = 0; tn < 4; ++tn) {
                    float p = __expf(s[tm][tn][r] - rmax[tm][r]);
                    s[tm][tn][r] = p;
                    ssum += p;
                }
#pragma unroll
                for (int d = 1; d < 16; d <<= 1) ssum += __shfl_xor(ssum, d, 16);
                rinv[tm][r] = 1.0f / ssum;
            }
        // write P (bf16, A-operand layout; cols 49..63 exact zero = K pad)
#pragma unroll
        for (int tm = 0; tm < 4; ++tm)
#pragma unroll
            for (int r = 0; r < 4; ++r) {
                int row = tm * 16 + crow + r;
                if (row < 49) {
                    float ri = rinv[tm][r];
#pragma unroll
                    for (int tn = 0; tn < 4; ++tn) {
                        int n = tn * 16 + lane15;
                        u16 hv = (n < 49) ? f2b(s[tm][tn][r] * ri) : (u16)0;
                        *(u16*)(pbase + (row * P_STRIDE + n) * 2) = hv;
                    }
                }
            }
        __syncthreads();   // insurance: cross-lane P write -> A-frag read
        f32x4 ov[4][2];
#pragma unroll
        for (int tm = 0; tm < 4; ++tm) {
            ov[tm][0] = (f32x4){0.f, 0.f, 0.f, 0.f};
            ov[tm][1] = (f32x4){0.f, 0.f, 0.f, 0.f};
        }
#pragma unroll
        for (int ks = 0; ks < 2; ++ks) {
            int kb = (ks * 32 + quad * 8) * 2;
            bf16x8 bv0 = *(const bf16x8*)(smem + VT_OFF + (h * 32 + lane15) * (VT_STRIDE * 2) + kb);
            bf16x8 bv1 = *(const bf16x8*)(smem + VT_OFF + (h * 32 + 16 + lane15) * (VT_STRIDE * 2) + kb);
#pragma unroll
            for (int tm = 0; tm < 4; ++tm) {
                bf16x8 ap = *(const bf16x8*)(pbase + mrowc[tm] * (P_STRIDE * 2) + kb);
                ov[tm][0] = __builtin_amdgcn_mfma_f32_16x16x32_bf16(ap, bv0, ov[tm][0], 0, 0, 0);
                ov[tm][1] = __builtin_amdgcn_mfma_f32_16x16x32_bf16(ap, bv1, ov[tm][1], 0, 0, 0);
            }
        }
#pragma unroll
        for (int tm = 0; tm < 4; ++tm)
#pragma unroll
            for (int r = 0; r < 4; ++r) {
                int row = tm * 16 + crow + r;
                if (row < 49) {
                    *(u16*)(smem + QK_OFF + (row * QK_STRIDE + h * 32 + lane15) * 2) = f2b(ov[tm][0][r]);
                    *(u16*)(smem + QK_OFF + (row * QK_STRIDE + h * 32 + 16 + lane15) * 2) = f2b(ov[tm][1][r]);
                }
            }
    }
    __syncthreads();

    // ---------------- stage 3: proj GEMM (M=64, N=256, K=256) + scatter ----------------
    for (int ci = 0; ci < 4; ++ci) {
        int o = (wv * 4 + ci) * 16 + lane15;      // 0..255
        f32x4 acc[4];
#pragma unroll
        for (int t = 0; t < 4; ++t) acc[t] = (f32x4){0.f, 0.f, 0.f, 0.f};
#pragma unroll
        for (int ks = 0; ks < 8; ++ks) {
            bf16x8 bfrag = load8(proj_w, o * 256 + ks * 32 + quad * 8, isbf);
            int cb = (ks * 32 + quad * 8) * 2;
#pragma unroll
            for (int tm = 0; tm < 4; ++tm) {
                bf16x8 afrag = *(const bf16x8*)(smem + QK_OFF + mrowc[tm] * (QK_STRIDE * 2) + cb);
                acc[tm] = __builtin_amdgcn_mfma_f32_16x16x32_bf16(afrag, bfrag, acc[tm], 0, 0, 0);
            }
        }
        float pb = loadf(proj_b, o, isbf);
#pragma unroll
        for (int tm = 0; tm < 4; ++tm)
#pragma unroll
            for (int r = 0; r < 4; ++r) {
                int row = tm * 16 + crow + r;
                if (row < 49) {
                    int rt = row / 7, ct = row - (row / 7) * 7;
                    int dh = (whi * 7 + rt + 3) % 56;
                    int dw = (wwi * 7 + ct + 3) % 56;
                    int oidx = ((b * 56 + dh) * 56 + dw) * 256 + o;
                    float v = acc[tm][r] + pb;
                    if (isbf) ((u16*)out)[oidx] = f2b(v);
                    else      ((float*)out)[oidx] = v;
                }
            }
    }
}

extern "C" void kernel_launch(void* const* d_in, const int* in_sizes, int n_in,
                              void* d_out, int out_size, void* d_ws, size_t ws_size,
                              hipStream_t stream) {
    (void)n_in; (void)d_ws; (void)ws_size; (void)out_size;
    const void* x        = d_in[0];
    const void* qkv_w    = d_in[1];
    const void* qkv_b    = d_in[2];
    const void* proj_w   = d_in[3];
    const void* proj_b   = d_in[4];
    const void* bias_tbl = d_in[5];

    int B = in_sizes[0] / (56 * 56 * 256);      // 32
    int nblk = B * 64;                          // one block per window

    hipFuncSetAttribute((const void*)swin_fused_kernel,
                        hipFuncAttributeMaxDynamicSharedMemorySize, SMEM_BYTES);

    swin_fused_kernel<<<dim3(nblk), dim3(256), SMEM_BYTES, stream>>>(
        x, qkv_w, qkv_b, proj_w, proj_b, bias_tbl, d_out);
}

// Round 4
// 565.172 us; speedup vs baseline: 1.4912x; 1.4912x over previous
//
#include <hip/hip_runtime.h>

typedef __attribute__((ext_vector_type(8))) short bf16x8;
typedef __attribute__((ext_vector_type(4))) float f32x4;
typedef unsigned short u16;

#define NTOK    49
#define SCALE   0.17677669529663687f
#define NEGBIG  -30000.0f
#define DIV7(v) (((v) * 9363) >> 16)          // exact for 0..63

// ---- LDS layout (bytes). 16-B aligned sections.
// EX region: Q-xchg(49x264) -> K-xchg -> VT(256x56,+pad) -> P(4 x 49x72)
#define EX_OFF     0
#define EX_BYTES   28704
#define EX_INIT_B  25872     // Q/K exchange writes 0..25871; 25872..28703 must be zeroed
#define XO_OFF     28704     // x-tile (49x264 bf16) -> O (49x264 bf16)
#define XO_BYTES   25872
#define BIAS_OFF   54576
#define BIAS_BYTES 2704      // 169*8 u16
#define SMEM_BYTES 57280     // < 64 KB -> static __shared__, 2 blocks/CU

static __device__ __forceinline__ float b2f(u16 u) {
    return __uint_as_float(((unsigned int)u) << 16);
}
static __device__ __forceinline__ u16 f2b(float f) {
    unsigned int x = __float_as_uint(f);
    x += 0x7fffu + ((x >> 16) & 1u);      // RNE
    return (u16)(x >> 16);
}
static __device__ __forceinline__ bf16x8 load8(const void* base, int eidx, int isbf) {
    if (isbf) return *(const bf16x8*)((const u16*)base + eidx);
    const float* f = (const float*)base + eidx;
    float4 a = *(const float4*)f;
    float4 c = *(const float4*)(f + 4);
    bf16x8 r;
    r[0] = (short)f2b(a.x); r[1] = (short)f2b(a.y); r[2] = (short)f2b(a.z); r[3] = (short)f2b(a.w);
    r[4] = (short)f2b(c.x); r[5] = (short)f2b(c.y); r[6] = (short)f2b(c.z); r[7] = (short)f2b(c.w);
    return r;
}
static __device__ __forceinline__ float loadf(const void* base, int i, int isbf) {
    return isbf ? b2f(((const u16*)base)[i]) : ((const float*)base)[i];
}
static __device__ __forceinline__ int region9(int gh, int gw) {
    return (gh < 49 ? 0 : (gh < 53 ? 1 : 2)) * 3 + (gw < 49 ? 0 : (gw < 53 ? 1 : 2));
}

__global__ void __launch_bounds__(256, 2)
swin_fused_v4(const void* __restrict__ x, const void* __restrict__ qkv_w,
              const void* __restrict__ qkv_b, const void* __restrict__ proj_w,
              const void* __restrict__ proj_b, const void* __restrict__ bias_tbl,
              void* __restrict__ out)
{
    __shared__ __align__(16) char smem[SMEM_BYTES];
    const int tid    = threadIdx.x;
    const int wv     = tid >> 6;
    const int lane   = tid & 63;
    const int lane15 = lane & 15;
    const int quad   = lane >> 4;
    const int crow   = quad << 2;

    const int win  = blockIdx.x;
    const int b    = win >> 6;
    const int wrem = win & 63;
    const int whi  = wrem >> 3;
    const int wwi  = wrem & 7;

    // ---- dtype sniff (wave-uniform, identical samples in every wave) ----
    int good = 0;
#pragma unroll
    for (int j = 0; j < 8; ++j) {
        u16 u = ((const u16*)qkv_w)[lane * 32 + j * 4];
        int e = (u >> 7) & 0xff;
        good += (e == 0 || (e >= 100 && e <= 140)) ? 1 : 0;
    }
#pragma unroll
    for (int d = 1; d < 64; d <<= 1) good += __shfl_xor(good, d, 64);
    const int isbf = (good > 300) ? 1 : 0;   // 512 samples: bf16 ~512, f32 ~90

    // ---- stage 0: gather x -> XO, bias table, zero EX uninit window ----
    for (int i = tid; i < NTOK * 32; i += 256) {
        int tok = i >> 5, ch = i & 31;
        int rt = DIV7(tok), ct = tok - rt * 7;
        int sh_ = whi * 7 + rt + 3; if (sh_ >= 56) sh_ -= 56;
        int sw_ = wwi * 7 + ct + 3; if (sw_ >= 56) sw_ -= 56;
        int idx = ((b * 56 + sh_) * 56 + sw_) * 256 + ch * 8;
        *(bf16x8*)(smem + XO_OFF + tok * 528 + ch * 16) = load8(x, idx, isbf);
    }
    for (int i = tid; i < 169 * 8; i += 256)
        *(u16*)(smem + BIAS_OFF + i * 2) = f2b(loadf(bias_tbl, i, isbf));
    {
        // Zero EX bytes [EX_INIT_B, EX_BYTES): never written by Q/K exchange but
        // readable as V^T pad -> must be finite (0 x Inf = NaN was the v3 bug).
        bf16x8 z8 = {0, 0, 0, 0, 0, 0, 0, 0};
        for (int i = tid; i < (EX_BYTES - EX_INIT_B) / 16; i += 256)
            *(bf16x8*)(smem + EX_OFF + EX_INIT_B + i * 16) = z8;
    }
    __syncthreads();

    int mrowc[4];
#pragma unroll
    for (int t = 0; t < 4; ++t) {
        int m = t * 16 + lane15;
        mrowc[t] = m < 49 ? m : 48;
    }

    bf16x8 fragQ[2][4], fragK[2][4], fragV[2][4];

    // ---- rounds Q and K: GEMM into EX, then capture frags to registers ----
#pragma unroll
    for (int rnd = 0; rnd < 2; ++rnd) {
        for (int ci = 0; ci < 4; ++ci) {
            int o = (wv * 4 + ci) * 16 + lane15;     // 0..255
            int orow = rnd * 256 + o;
            f32x4 acc[4];
#pragma unroll
            for (int t = 0; t < 4; ++t) acc[t] = (f32x4){0.f, 0.f, 0.f, 0.f};
#pragma unroll
            for (int ks = 0; ks < 8; ++ks) {
                bf16x8 bfrag = load8(qkv_w, orow * 256 + ks * 32 + quad * 8, isbf);
                int cb = (ks * 32 + quad * 8) * 2;
#pragma unroll
                for (int tm = 0; tm < 4; ++tm) {
                    bf16x8 afrag = *(const bf16x8*)(smem + XO_OFF + mrowc[tm] * 528 + cb);
                    acc[tm] = __builtin_amdgcn_mfma_f32_16x16x32_bf16(afrag, bfrag, acc[tm], 0, 0, 0);
                }
            }
            float bias = loadf(qkv_b, orow, isbf);
#pragma unroll
            for (int tm = 0; tm < 4; ++tm)
#pragma unroll
                for (int rr = 0; rr < 4; ++rr) {
                    int row = tm * 16 + crow + rr;
                    if (row < 49)
                        *(u16*)(smem + EX_OFF + (row * 264 + o) * 2) = f2b(acc[tm][rr] + bias);
                }
        }
        __syncthreads();
#pragma unroll
        for (int hi = 0; hi < 2; ++hi)
#pragma unroll
            for (int t = 0; t < 4; ++t) {
                bf16x8 f = *(const bf16x8*)(smem + EX_OFF +
                            (mrowc[t] * 264 + wv * 64 + hi * 32 + quad * 8) * 2);
                if (rnd == 0) fragQ[hi][t] = f; else fragK[hi][t] = f;
            }
        __syncthreads();
    }

    // ---- round V: GEMM into EX as V^T [256 ch][stride 56], capture bv frags ----
    for (int ci = 0; ci < 4; ++ci) {
        int vch = (wv * 4 + ci) * 16 + lane15;       // 0..255
        int orow = 512 + vch;
        f32x4 acc[4];
#pragma unroll
        for (int t = 0; t < 4; ++t) acc[t] = (f32x4){0.f, 0.f, 0.f, 0.f};
#pragma unroll
        for (int ks = 0; ks < 8; ++ks) {
            bf16x8 bfrag = load8(qkv_w, orow * 256 + ks * 32 + quad * 8, isbf);
            int cb = (ks * 32 + quad * 8) * 2;
#pragma unroll
            for (int tm = 0; tm < 4; ++tm) {
                bf16x8 afrag = *(const bf16x8*)(smem + XO_OFF + mrowc[tm] * 528 + cb);
                acc[tm] = __builtin_amdgcn_mfma_f32_16x16x32_bf16(afrag, bfrag, acc[tm], 0, 0, 0);
            }
        }
        float bias = loadf(qkv_b, orow, isbf);
#pragma unroll
        for (int tm = 0; tm < 4; ++tm)
#pragma unroll
            for (int rr = 0; rr < 4; ++rr) {
                int row = tm * 16 + crow + rr;
                if (row < 49)
                    *(u16*)(smem + EX_OFF + (vch * 56 + row) * 2) = f2b(acc[tm][rr] + bias);
            }
    }
    __syncthreads();
#pragma unroll
    for (int hi = 0; hi < 2; ++hi)
#pragma unroll
        for (int f = 0; f < 4; ++f) {
            int vrow = wv * 64 + hi * 32 + (f & 1) * 16 + lane15;
            int vcol = (f >> 1) * 32 + quad * 8;     // cols >=49: leftover K (finite) or zeroed pad
            fragV[hi][f] = *(const bf16x8*)(smem + EX_OFF + (vrow * 56 + vcol) * 2);
        }
    __syncthreads();   // all bv captured before P overwrites EX

    // ---- per-n (column) constants, head-independent ----
    int nval[4], regn_[4], idxn[4];
#pragma unroll
    for (int tn = 0; tn < 4; ++tn) {
        int n = tn * 16 + lane15;
        nval[tn] = (n < 49);
        int nc = n < 49 ? n : 48;
        int rn = DIV7(nc), cn = nc - rn * 7;
        regn_[tn] = region9(whi * 7 + rn, wwi * 7 + cn);
        idxn[tn]  = (6 - rn) * 13 + (6 - cn);
    }

    // ---- attention: 2 heads per wave; P overlays EX (per-wave slice) ----
    char* pbase = smem + EX_OFF + wv * 7056;
#pragma unroll
    for (int hi = 0; hi < 2; ++hi) {
        int h = wv * 2 + hi;
        f32x4 s[4][4];
#pragma unroll
        for (int tm = 0; tm < 4; ++tm)
#pragma unroll
            for (int tn = 0; tn < 4; ++tn) {
                f32x4 z = {0.f, 0.f, 0.f, 0.f};
                s[tm][tn] = __builtin_amdgcn_mfma_f32_16x16x32_bf16(fragQ[hi][tm], fragK[hi][tn], z, 0, 0, 0);
            }
#pragma unroll
        for (int tm = 0; tm < 4; ++tm)
#pragma unroll
            for (int rr = 0; rr < 4; ++rr) {
                int m = tm * 16 + crow + rr;
                int mc2 = m < 49 ? m : 48;
                int rm = DIV7(mc2), cm = mc2 - rm * 7;
                int regm = region9(whi * 7 + rm, wwi * 7 + cm);
                int basem = rm * 13 + cm;
                float e[4];
                float mv = NEGBIG;
#pragma unroll
                for (int tn = 0; tn < 4; ++tn) {
                    float v;
                    if (nval[tn]) {
                        int idx = basem + idxn[tn];
                        float bv = b2f(*(const u16*)(smem + BIAS_OFF + (idx * 8 + h) * 2));
                        v = s[tm][tn][rr] * SCALE + bv + ((regm != regn_[tn]) ? -100.0f : 0.0f);
                    } else v = NEGBIG;
                    e[tn] = v;
                    mv = fmaxf(mv, v);
                }
#pragma unroll
                for (int d = 1; d < 16; d <<= 1) mv = fmaxf(mv, __shfl_xor(mv, d, 16));
                float ssum = 0.f;
#pragma unroll
                for (int tn = 0; tn < 4; ++tn) {
                    e[tn] = __expf(e[tn] - mv);
                    ssum += e[tn];
                }
#pragma unroll
                for (int d = 1; d < 16; d <<= 1) ssum += __shfl_xor(ssum, d, 16);
                float ri = 1.0f / ssum;
                if (m < 49) {
#pragma unroll
                    for (int tn = 0; tn < 4; ++tn) {
                        int n = tn * 16 + lane15;
                        u16 hv = nval[tn] ? f2b(e[tn] * ri) : (u16)0;   // cols 49..63 exact 0
                        *(u16*)(pbase + (m * 72 + n) * 2) = hv;
                    }
                }
            }
        __syncthreads();   // insurance: cross-lane P write -> A-frag read (v2 had this and passed)
        // PV
        f32x4 ov0[4], ov1[4];
#pragma unroll
        for (int tm = 0; tm < 4; ++tm) {
            ov0[tm] = (f32x4){0.f, 0.f, 0.f, 0.f};
            ov1[tm] = (f32x4){0.f, 0.f, 0.f, 0.f};
        }
#pragma unroll
        for (int ks = 0; ks < 2; ++ks) {
            int kb = (ks * 32 + quad * 8) * 2;
#pragma unroll
            for (int tm = 0; tm < 4; ++tm) {
                bf16x8 ap = *(const bf16x8*)(pbase + mrowc[tm] * 144 + kb);
                ov0[tm] = __builtin_amdgcn_mfma_f32_16x16x32_bf16(ap, fragV[hi][ks * 2],     ov0[tm], 0, 0, 0);
                ov1[tm] = __builtin_amdgcn_mfma_f32_16x16x32_bf16(ap, fragV[hi][ks * 2 + 1], ov1[tm], 0, 0, 0);
            }
        }
#pragma unroll
        for (int tm = 0; tm < 4; ++tm)
#pragma unroll
            for (int rr = 0; rr < 4; ++rr) {
                int row = tm * 16 + crow + rr;
                if (row < 49) {
                    *(u16*)(smem + XO_OFF + (row * 264 + h * 32 + lane15) * 2)      = f2b(ov0[tm][rr]);
                    *(u16*)(smem + XO_OFF + (row * 264 + h * 32 + 16 + lane15) * 2) = f2b(ov1[tm][rr]);
                }
            }
    }
    __syncthreads();   // O complete before proj reads all channels

    // ---- proj (transposed): out^T = proj_w x O^T; C rows=out-ch, cols=token ----
    int obase[4];
#pragma unroll
    for (int tn = 0; tn < 4; ++tn) {
        int n = tn * 16 + lane15;
        int nc = n < 49 ? n : 48;
        int rn = DIV7(nc), cn = nc - rn * 7;
        int dh = whi * 7 + rn + 3; if (dh >= 56) dh -= 56;
        int dw = wwi * 7 + cn + 3; if (dw >= 56) dw -= 56;
        obase[tn] = ((b * 56 + dh) * 56 + dw) * 256;
    }
    for (int ci = 0; ci < 4; ++ci) {
        int mch = wv * 4 + ci;                       // out-channel chunk 0..15
        f32x4 acc[4];
#pragma unroll
        for (int t = 0; t < 4; ++t) acc[t] = (f32x4){0.f, 0.f, 0.f, 0.f};
#pragma unroll
        for (int ks = 0; ks < 8; ++ks) {
            bf16x8 af = load8(proj_w, (mch * 16 + lane15) * 256 + ks * 32 + quad * 8, isbf);
            int cb = (ks * 32 + quad * 8) * 2;
#pragma unroll
            for (int tn = 0; tn < 4; ++tn) {
                bf16x8 bo = *(const bf16x8*)(smem + XO_OFF + mrowc[tn] * 528 + cb);
                acc[tn] = __builtin_amdgcn_mfma_f32_16x16x32_bf16(af, bo, acc[tn], 0, 0, 0);
            }
        }
#pragma unroll
        for (int rr = 0; rr < 4; ++rr) {
            int ch = mch * 16 + crow + rr;           // lane-uniform
            float pb = loadf(proj_b, ch, isbf);
#pragma unroll
            for (int tn = 0; tn < 4; ++tn) {
                if (nval[tn]) {
                    float v = acc[tn][rr] + pb;
                    int oi = obase[tn] + ch;
                    if (isbf) ((u16*)out)[oi] = f2b(v);
                    else      ((float*)out)[oi] = v;
                }
            }
        }
    }
}

extern "C" void kernel_launch(void* const* d_in, const int* in_sizes, int n_in,
                              void* d_out, int out_size, void* d_ws, size_t ws_size,
                              hipStream_t stream) {
    (void)n_in; (void)d_ws; (void)ws_size; (void)out_size;
    int B = in_sizes[0] / (56 * 56 * 256);      // 32
    int nblk = B * 64;                          // one block per window

    swin_fused_v4<<<dim3(nblk), dim3(256), 0, stream>>>(
        d_in[0], d_in[1], d_in[2], d_in[3], d_in[4], d_in[5], d_out);
}